// Round 5
// baseline (38.326 us; speedup 1.0000x reference)
//
#include <hip/hip_runtime.h>

// EnergyPool2d: N=16, C=64, H=W=128, 3x3 windows stride 1 -> Ho=Wo=126.
// +1 at first-argmax flat index, -1 at first-argmin flat index per window.
// R5: 4x4-window tiles (6 rows x 8 cols input, 12 float4 loads / 16 windows).
// Separable in-tile stats: per (row, col-offset) h-stat via max3 + equality
// first-index select; per window one max3 over 3 row h-stats + backward
// equality select. Reproduces row-major first-occurrence tie-break exactly.

#define HH 128
#define WW 128
#define HO 126
#define WO 126
#define PLANE (HH * WW)   // 16384
#define NPLANES (16 * 64) // 1024
#define BLOCK 1024

__global__ __launch_bounds__(BLOCK, 8)
void energy_pool2d_kernel(const float* __restrict__ x, float* __restrict__ out) {
    __shared__ int cnt[PLANE]; // 64 KB

    const int tid = threadIdx.x;
    const int plane = blockIdx.x;
    const float* __restrict__ xp = x + (size_t)plane * PLANE;

    // Zero the LDS count plane.
    int4* c4 = (int4*)cnt;
#pragma unroll
    for (int i = 0; i < PLANE / 4 / BLOCK; ++i)
        c4[tid + i * BLOCK] = make_int4(0, 0, 0, 0);
    __syncthreads();

    // One 4x4-window tile per thread: 32 col-tiles x 32 row-tiles.
    const int rt = tid >> 5;        // 0..31
    const int ct = tid & 31;        // 0..31
    const int wr0 = rt * 4;         // first window row (0..124)
    const int j0 = ct * 4;          // first window col (0..124)
    const bool cfull = (ct < 31);   // ct=31: only window col-offsets 0,1 valid
    const bool rfull = (rt < 31);   // rt=31: only window row-offsets 0,1 valid
    const int base = wr0 * WW + j0;
    const float* __restrict__ p = xp + base;

    // Load 6 rows x 8 cols; clamp addresses at edges (masked windows never
    // consume the duplicated data).
    float r[6][8];
#pragma unroll
    for (int q = 0; q < 6; ++q) {
        const int qs = (q >= 4 && !rfull) ? 3 : q;  // bottom-edge row clamp
        const float* rowp = p + qs * WW;
        const float4 a = *(const float4*)(rowp);
        const float4 b = *(const float4*)(rowp + (cfull ? 4 : 0)); // right clamp
        r[q][0] = a.x; r[q][1] = a.y; r[q][2] = a.z; r[q][3] = a.w;
        r[q][4] = b.x; r[q][5] = b.y; r[q][6] = b.z; r[q][7] = b.w;
    }

#pragma unroll
    for (int o = 0; o < 4; ++o) {   // window col-offset within tile
        // h-stats for the 6 rows at this offset (flat-relative indices).
        float hM[6], hm[6];
        int hA[6], ha[6];
#pragma unroll
        for (int q = 0; q < 6; ++q) {
            const float v0 = r[q][o], v1 = r[q][o + 1], v2 = r[q][o + 2];
            const int f0 = q * WW + o;
            float M = fmaxf(fmaxf(v0, v1), v2);       // v_max3_f32
            int A = f0 + 2;
            if (v1 == M) A = f0 + 1;
            if (v0 == M) A = f0;                      // first col achieving M
            float m = fminf(fminf(v0, v1), v2);       // v_min3_f32
            int a = f0 + 2;
            if (v1 == m) a = f0 + 1;
            if (v0 == m) a = f0;
            hM[q] = M; hA[q] = A; hm[q] = m; ha[q] = a;
        }
        const bool oval = (o < 2) || cfull;
#pragma unroll
        for (int q = 0; q < 4; ++q) { // window row-offset within tile
            const bool qval = (q < 2) || rfull;
            if (oval && qval) {
                const float WM = fmaxf(fmaxf(hM[q], hM[q + 1]), hM[q + 2]);
                int wA = hA[q + 2];
                if (hM[q + 1] == WM) wA = hA[q + 1];
                if (hM[q] == WM) wA = hA[q];          // first row achieving WM
                const float Wm = fminf(fminf(hm[q], hm[q + 1]), hm[q + 2]);
                int wa = ha[q + 2];
                if (hm[q + 1] == Wm) wa = ha[q + 1];
                if (hm[q] == Wm) wa = ha[q];
                atomicAdd(&cnt[base + wA], 1);
                atomicAdd(&cnt[base + wa], -1);
            }
        }
    }
    __syncthreads();

    // Coalesced writeout: int -> float, float4 stores (whole plane overwritten).
    float4* __restrict__ o4 = (float4*)(out + (size_t)plane * PLANE);
#pragma unroll
    for (int i = 0; i < PLANE / 4 / BLOCK; ++i) {
        const int4 ci = c4[tid + i * BLOCK];
        o4[tid + i * BLOCK] =
            make_float4((float)ci.x, (float)ci.y, (float)ci.z, (float)ci.w);
    }
}

extern "C" void kernel_launch(void* const* d_in, const int* in_sizes, int n_in,
                              void* d_out, int out_size, void* d_ws, size_t ws_size,
                              hipStream_t stream) {
    const float* x = (const float*)d_in[0];
    float* out = (float*)d_out;
    energy_pool2d_kernel<<<NPLANES, BLOCK, 0, stream>>>(x, out);
}